// Round 12
// baseline (420.984 us; speedup 1.0000x reference)
//
#include <hip/hip_runtime.h>
#include <hip/hip_bf16.h>
#include <hip/hip_cooperative_groups.h>

namespace cg = cooperative_groups;

#define NN 50000
#define NE 800000
#define DIN 128
#define DEIN 32
#define PD 192          // P row: [0:64) f_ni, [64:128) f_nj, [128:192) h_src(node proj)
#define NEG_SLOPE 0.2f
#define CSR_NB 196      // ceil(NN/256)
#define CSR_GRID 512

typedef __bf16 bf16x8 __attribute__((ext_vector_type(8)));
typedef __bf16 bf16x4 __attribute__((ext_vector_type(4)));
typedef float f32x4 __attribute__((ext_vector_type(4)));
using bf16 = __hip_bfloat16;

__device__ inline float b2f(__bf16 b) {
    unsigned short u = __builtin_bit_cast(unsigned short, b);
    return __uint_as_float((unsigned)u << 16);
}

__device__ inline bf16x8 load8_f32_to_bf16(const float* p) {
    f32x4 a = *reinterpret_cast<const f32x4*>(p);
    f32x4 b = *reinterpret_cast<const f32x4*>(p + 4);
    bf16x8 r;
#pragma unroll
    for (int j = 0; j < 4; j++) {
        r[j]     = (__bf16)a[j];
        r[j + 4] = (__bf16)b[j];
    }
    return r;
}

__device__ inline void async_copy16(const void* g, void* lds) {
    __builtin_amdgcn_global_load_lds(
        (const __attribute__((address_space(1))) void*)g,
        (__attribute__((address_space(3))) void*)lds, 16, 0, 0);
}

// ---------------- K1: P = nfeats @ [W_ni | W_nj | W_node] (+ zero counts) --------------
// 512 threads / 8 waves / 128 rows per block; W staged once, transposed LDS.
__global__ __launch_bounds__(512) void k_node_gemm(
    const float* __restrict__ nfeats,
    const float* __restrict__ Wni, const float* __restrict__ Wnj,
    const float* __restrict__ Wnode,
    bf16* __restrict__ P, int* __restrict__ counts)
{
    __shared__ __align__(16) __bf16 sW[192][136];   // 52.2KB, [col][k]
    const int t = threadIdx.x;
    const int lane = t & 63;
    const int wid  = t >> 6;
    const int lo = lane & 15, hi = lane >> 4;

    {   // fused: zero the histogram buffer
        int z = blockIdx.x * 512 + t;
        if (z < NN) counts[z] = 0;
    }

    const float* tabs[3] = {Wni, Wnj, Wnode};
#pragma unroll
    for (int tb = 0; tb < 3; tb++) {
#pragma unroll
        for (int q = 0; q < 4; q++) {
            int flat = t + q * 512;             // 2048 f32x4 per table
            int k  = flat >> 4;
            int c4 = (flat & 15) * 4;
            f32x4 w4 = *reinterpret_cast<const f32x4*>(&tabs[tb][k * 64 + c4]);
#pragma unroll
            for (int i = 0; i < 4; i++)
                sW[tb * 64 + c4 + i][k] = (__bf16)w4[i];
        }
    }

    const int rbase = blockIdx.x * 128 + wid * 16;
    bf16x8 afrag[4];
#pragma unroll
    for (int kk = 0; kk < 4; kk++) {
        int row = rbase + lo; if (row >= NN) row = NN - 1;
        afrag[kk] = load8_f32_to_bf16(&nfeats[(size_t)row*DIN + kk*32 + hi*8]);
    }
    __syncthreads();

#pragma unroll
    for (int ct = 0; ct < 12; ct++) {
        f32x4 acc = {0.f, 0.f, 0.f, 0.f};
#pragma unroll
        for (int kk = 0; kk < 4; kk++) {
            bf16x8 bfrag = *reinterpret_cast<const bf16x8*>(&sW[ct*16 + lo][kk*32 + hi*8]);
            acc = __builtin_amdgcn_mfma_f32_16x16x32_bf16(afrag[kk], bfrag, acc, 0, 0, 0);
        }
#pragma unroll
        for (int r = 0; r < 4; r++) {
            int row = rbase + hi*4 + r;
            if (row < NN) P[(size_t)row*PD + ct*16 + lo] = __float2bfloat16(acc[r]);
        }
    }
}

// ---------------- K-CSR: cooperative hist + scan + scatter (1 kernel, 3 grid syncs) ----
__global__ __launch_bounds__(256) void k_csr(
    const int* __restrict__ dst, const int* __restrict__ src,
    int* __restrict__ counts, int* __restrict__ offsets,
    int* __restrict__ cursor, int* __restrict__ eidx,
    int* __restrict__ srcp, int* __restrict__ bsum)
{
    cg::grid_group grid = cg::this_grid();
    const int t = threadIdx.x;
    const int b = blockIdx.x;
    const int gid = b * 256 + t;
    const int gsz = CSR_GRID * 256;
    const int lane = t & 63, wid = t >> 6;
    __shared__ int ws[4];
    __shared__ int sbp;

    // phase 1: histogram (counts zeroed by k_node_gemm)
    for (int i = gid; i < NE; i += gsz)
        atomicAdd(&counts[dst[i]], 1);
    grid.sync();

    // phase 2a: per-block sums
    if (b < CSR_NB) {
        int v = (gid < NN) ? counts[gid] : 0;
        int s = v;
#pragma unroll
        for (int sh = 1; sh < 64; sh <<= 1) s += __shfl_xor(s, sh);
        if (lane == 0) ws[wid] = s;
        __syncthreads();
        if (t == 0) bsum[b] = ws[0] + ws[1] + ws[2] + ws[3];
    }
    grid.sync();

    // phase 2b: each block redundantly scans bsum[0..255] for its prefix,
    // then intra-block scan of counts -> offsets/cursor.
    if (b < CSR_NB) {
        int bv = (t < CSR_NB) ? bsum[t] : 0;
        int bs = bv;
#pragma unroll
        for (int sh = 1; sh < 64; sh <<= 1) { int u = __shfl_up(bs, sh); if (lane >= sh) bs += u; }
        __syncthreads();            // ws reuse (2a's read done pre-gridsync)
        if (lane == 63) ws[wid] = bs;
        __syncthreads();
        int woffb = 0;
        for (int k = 0; k < wid; k++) woffb += ws[k];
        if (t == b) sbp = woffb + bs - bv;   // exclusive prefix of block b
        __syncthreads();
        const int bpre_b = sbp;

        int v = (gid < NN) ? counts[gid] : 0;
        int sc = v;
#pragma unroll
        for (int sh = 1; sh < 64; sh <<= 1) { int u = __shfl_up(sc, sh); if (lane >= sh) sc += u; }
        if (lane == 63) ws[wid] = sc;       // safe: previous ws reads done (loop above)
        __syncthreads();
        int woff = 0;
        for (int k = 0; k < wid; k++) woff += ws[k];
        const int ex = bpre_b + woff + sc - v;
        if (gid < NN) { offsets[gid] = ex; cursor[gid] = ex; }
    }
    if (gid == 0) offsets[NN] = NE;
    grid.sync();

    // phase 3: scatter
    for (int i = gid; i < NE; i += gsz) {
        int p = atomicAdd(&cursor[dst[i]], 1);
        eidx[p] = i;
        srcp[p] = src[i];
    }
}

// ---------------- K2: fused edge stage (R9 structure) ----------------
// 512 threads / 8 waves / 128 edges. Per-wave async P gathers; MFMA; per-wave
// XOR-swizzled transpose in own tile; P adds as ds_read_b64; logit = 2 shfl.
__global__ __launch_bounds__(512) void k_edge(
    const float* __restrict__ efeats,
    const float* __restrict__ Wf,     // [32][64] f32
    const float* __restrict__ attn,   // [64] f32
    const float* __restrict__ bias,   // [64] f32
    const bf16* __restrict__ P,       // [NN][192] bf16
    const int* __restrict__ src, const int* __restrict__ dst,
    float* __restrict__ f_out,        // [NE][64] f32
    float* __restrict__ el)           // [NE][4] = exp(logit)
{
    // [0,32K): per-wave 4KB tiles (gather sP, then transpose buf); [32K,36K): sWf
    __shared__ __align__(16) char smem[36864];
    __bf16* sWf = reinterpret_cast<__bf16*>(smem + 32768);   // [64 col][32 k]
    const int t = threadIdx.x;
    const int lane = t & 63, wid = t >> 6;
    const int lo = lane & 15, hi = lane >> 4;
    const int e0w = blockIdx.x * 128 + wid * 16;
    const int c4 = (lane & 15) * 4;

    // stage Wf transposed (all threads)
    {
        int k  = t >> 4;
        int cc = (t & 15) * 4;
        f32x4 w4 = *reinterpret_cast<const f32x4*>(&Wf[k * 64 + cc]);
#pragma unroll
        for (int i = 0; i < 4; i++) sWf[(cc + i)*32 + k] = (__bf16)w4[i];
    }
    __syncthreads();

    // per-wave: node indices for this wave's 16 edges (lanes 0..31)
    int sd = 0;
    if (lane < 32) sd = (lane < 16) ? src[e0w + lane] : dst[e0w + lane - 16];

    // per-wave async gathers: 256 x 16B -> spw[2][16][64] bf16 row-major
    __bf16* spw = reinterpret_cast<__bf16*>(smem) + wid * 2048;
#pragma unroll
    for (int q = 0; q < 4; q++) {
        const int c = lane + q * 64;
        const int table = c >> 7, row16 = (c >> 3) & 15, part = c & 7;
        const int nid = __shfl(sd, table * 16 + row16);
        const bf16* g = P + (size_t)nid * PD + table * 64 + part * 8;
        async_copy16(g, reinterpret_cast<__bf16*>(smem) + (size_t)(wid*2048 + q*512));
    }

    bf16x8 afrag = load8_f32_to_bf16(&efeats[(size_t)(e0w + lo)*DEIN + hi*8]);
    bf16x8 bfr[4];
#pragma unroll
    for (int ct = 0; ct < 4; ct++)
        bfr[ct] = *reinterpret_cast<const bf16x8*>(&sWf[(ct*16 + lo)*32 + hi*8]);

    f32x4 att4  = *reinterpret_cast<const f32x4*>(&attn[c4]);
    f32x4 bias4 = *reinterpret_cast<const f32x4*>(&bias[c4]);

    // wait for this wave's own gathers (+ afrag); vmcnt is per-wave
    asm volatile("s_waitcnt vmcnt(0)" ::: "memory");
    __builtin_amdgcn_sched_barrier(0);

    // P pre-reads for the post-transpose positions: one b64 per (table,q)
    bf16x4 pi4[4], pj4[4];
#pragma unroll
    for (int q = 0; q < 4; q++) {
        const int lrow = (lane >> 4) + q*4;
        pi4[q] = *reinterpret_cast<const bf16x4*>(&spw[lrow*64 + c4]);
        pj4[q] = *reinterpret_cast<const bf16x4*>(&spw[1024 + lrow*64 + c4]);
    }

    f32x4 accv[4];
#pragma unroll
    for (int ct = 0; ct < 4; ct++) {
        f32x4 z = {0.f, 0.f, 0.f, 0.f};
        accv[ct] = __builtin_amdgcn_mfma_f32_16x16x32_bf16(afrag, bfr[ct], z, 0, 0, 0);
    }

    // per-wave swizzled transpose into OWN 4KB tile; wave-local DS is in-order,
    // pi4/pj4 reads above already issued -> no block barrier needed.
    float* sOutF = reinterpret_cast<float*>(smem + wid * 4096);   // [16][64] f32
#pragma unroll
    for (int ct = 0; ct < 4; ct++)
#pragma unroll
        for (int r = 0; r < 4; r++)
            sOutF[(hi*4 + r)*64 + ((ct*16 + lo) ^ (hi << 4))] = accv[ct][r];

#pragma unroll
    for (int q = 0; q < 4; q++) {
        const int lrow = (lane >> 4) + q*4;
        f32x4 o = *reinterpret_cast<const f32x4*>(&sOutF[lrow*64 + (c4 ^ (q << 4))]);
        f32x4 x;
#pragma unroll
        for (int i = 0; i < 4; i++) {
            float xv = o[i] + b2f(pi4[q][i]) + b2f(pj4[q][i]) + bias4[i];
            x[i] = xv > 0.f ? xv : NEG_SLOPE * xv;
        }
        *reinterpret_cast<f32x4*>(&f_out[(size_t)(e0w + lrow)*64 + c4]) = x;
        float partial = x[0]*att4[0] + x[1]*att4[1] + x[2]*att4[2] + x[3]*att4[3];
        partial += __shfl_xor(partial, 1);
        partial += __shfl_xor(partial, 2);
        const float ev = __expf(partial);
        if ((lane & 3) == 0)
            el[(size_t)(e0w + lrow)*4 + ((lane & 15) >> 2)] = ev;
    }
}

// ---------------- K4: single-pass aggregation (a=exp stored; no max needed) ----------
__global__ __launch_bounds__(256) void k_aggregate(
    const int* __restrict__ offsets, const int* __restrict__ eidx,
    const int* __restrict__ srcp, const float* __restrict__ el,
    const bf16* __restrict__ P, float* __restrict__ h_out)
{
    const int lane = threadIdx.x & 63;
    const int wid  = threadIdx.x >> 6;
    const int n = blockIdx.x * 4 + wid;
    if (n >= NN) return;
    const int off0 = offsets[n], off1 = offsets[n + 1];
    const int h4 = lane & 3;        // head for load phase
    const int slot4 = lane >> 2;    // 16 slots

    float denp = 0.f, acc = 0.f;
    for (int c0 = off0; c0 < off1; c0 += 16) {
        const int cnt = off1 - c0;
        float a_ld = 0.f;
        int s_ld = 0;
        if (slot4 < cnt) {
            const int e = eidx[c0 + slot4];
            a_ld = el[(size_t)e*4 + h4];
            s_ld = srcp[c0 + slot4];
        }
        denp += a_ld;
#pragma unroll
        for (int q = 0; q < 16; q++) {
            if (q < cnt) {   // wave-uniform tail guard
                const float wq = __shfl(a_ld, (q << 2) | (lane >> 4));
                const int   sq = __shfl(s_ld, q << 2);
                acc += wq * __bfloat162float(P[(size_t)sq*PD + 128 + lane]);
            }
        }
    }
    denp += __shfl_xor(denp, 4);
    denp += __shfl_xor(denp, 8);
    denp += __shfl_xor(denp, 16);
    denp += __shfl_xor(denp, 32);
    const float den = __shfl(denp, lane >> 4);
    h_out[(size_t)n*64 + lane] = (off1 > off0) ? acc / den : 0.f;
}

extern "C" void kernel_launch(void* const* d_in, const int* in_sizes, int n_in,
                              void* d_out, int out_size, void* d_ws, size_t ws_size,
                              hipStream_t stream) {
    const float* nfeats = (const float*)d_in[0];
    const float* efeats = (const float*)d_in[1];
    const float* Wni    = (const float*)d_in[2];
    const float* Wnj    = (const float*)d_in[3];
    const float* Wfij   = (const float*)d_in[4];
    const float* Wnode  = (const float*)d_in[5];
    const float* attn   = (const float*)d_in[6];
    const float* bias   = (const float*)d_in[7];
    const int*   src    = (const int*)d_in[8];
    const int*   dst    = (const int*)d_in[9];

    float* h_out = (float*)d_out;                           // [NN*64]
    float* f_out = (float*)d_out + (size_t)NN * 64;         // [NE*64]

    char* ws = (char*)d_ws;
    size_t off = 0;
    auto carve = [&](size_t bytes) -> void* {
        void* p = ws + off;
        off = (off + bytes + 255) & ~(size_t)255;
        return p;
    };
    bf16*  P       = (bf16*) carve((size_t)NN * PD * sizeof(bf16));
    float* el      = (float*)carve((size_t)NE * 4 * sizeof(float));
    int*   counts  = (int*)  carve((size_t)NN * sizeof(int));
    int*   cursor  = (int*)  carve((size_t)NN * sizeof(int));
    int*   offsets = (int*)  carve((size_t)(NN + 1) * sizeof(int));
    int*   eidx    = (int*)  carve((size_t)NE * sizeof(int));
    int*   srcp    = (int*)  carve((size_t)NE * sizeof(int));
    int*   bsum    = (int*)  carve((size_t)256 * sizeof(int));
    (void)ws_size; (void)in_sizes; (void)n_in; (void)out_size;

    hipLaunchKernelGGL(k_node_gemm, dim3((NN + 127) / 128), dim3(512), 0, stream,
                       nfeats, Wni, Wnj, Wnode, P, counts);

    {
        void* args[] = { (void*)&dst, (void*)&src, (void*)&counts, (void*)&offsets,
                         (void*)&cursor, (void*)&eidx, (void*)&srcp, (void*)&bsum };
        hipLaunchCooperativeKernel((const void*)k_csr, dim3(CSR_GRID), dim3(256),
                                   args, 0, stream);
    }

    hipLaunchKernelGGL(k_edge, dim3(NE / 128), dim3(512), 0, stream,
                       efeats, Wfij, attn, bias, P, src, dst, f_out, el);
    hipLaunchKernelGGL(k_aggregate, dim3((NN + 3) / 4), dim3(256), 0, stream,
                       offsets, eidx, srcp, el, P, h_out);
}

// Round 13
// 251.569 us; speedup vs baseline: 1.6734x; 1.6734x over previous
//
#include <hip/hip_runtime.h>
#include <hip/hip_bf16.h>

#define NN 50000
#define NE 800000
#define DIN 128
#define DEIN 32
#define PD 192          // P row: [0:64) f_ni, [64:128) f_nj, [128:192) h_src(node proj)
#define NEG_SLOPE 0.2f

typedef __bf16 bf16x8 __attribute__((ext_vector_type(8)));
typedef __bf16 bf16x4 __attribute__((ext_vector_type(4)));
typedef float f32x4 __attribute__((ext_vector_type(4)));
using bf16 = __hip_bfloat16;

__device__ inline float b2f(__bf16 b) {
    unsigned short u = __builtin_bit_cast(unsigned short, b);
    return __uint_as_float((unsigned)u << 16);
}

__device__ inline bf16x8 load8_f32_to_bf16(const float* p) {
    f32x4 a = *reinterpret_cast<const f32x4*>(p);
    f32x4 b = *reinterpret_cast<const f32x4*>(p + 4);
    bf16x8 r;
#pragma unroll
    for (int j = 0; j < 4; j++) {
        r[j]     = (__bf16)a[j];
        r[j + 4] = (__bf16)b[j];
    }
    return r;
}

__device__ inline void async_copy16(const void* g, void* lds) {
    __builtin_amdgcn_global_load_lds(
        (const __attribute__((address_space(1))) void*)g,
        (__attribute__((address_space(3))) void*)lds, 16, 0, 0);
}

// ---------------- K1: P = nfeats @ [W_ni | W_nj | W_node] (+ zero counts) --------------
// 512 threads / 8 waves / 128 rows per block; W staged once, transposed LDS.
__global__ __launch_bounds__(512) void k_node_gemm(
    const float* __restrict__ nfeats,
    const float* __restrict__ Wni, const float* __restrict__ Wnj,
    const float* __restrict__ Wnode,
    bf16* __restrict__ P, int* __restrict__ counts)
{
    __shared__ __align__(16) __bf16 sW[192][136];   // 52.2KB, [col][k]
    const int t = threadIdx.x;
    const int lane = t & 63;
    const int wid  = t >> 6;
    const int lo = lane & 15, hi = lane >> 4;

    {   // fused: zero the histogram buffer
        int z = blockIdx.x * 512 + t;
        if (z < NN) counts[z] = 0;
    }

    const float* tabs[3] = {Wni, Wnj, Wnode};
#pragma unroll
    for (int tb = 0; tb < 3; tb++) {
#pragma unroll
        for (int q = 0; q < 4; q++) {
            int flat = t + q * 512;             // 2048 f32x4 per table
            int k  = flat >> 4;
            int c4 = (flat & 15) * 4;
            f32x4 w4 = *reinterpret_cast<const f32x4*>(&tabs[tb][k * 64 + c4]);
#pragma unroll
            for (int i = 0; i < 4; i++)
                sW[tb * 64 + c4 + i][k] = (__bf16)w4[i];
        }
    }

    const int rbase = blockIdx.x * 128 + wid * 16;
    bf16x8 afrag[4];
#pragma unroll
    for (int kk = 0; kk < 4; kk++) {
        int row = rbase + lo; if (row >= NN) row = NN - 1;
        afrag[kk] = load8_f32_to_bf16(&nfeats[(size_t)row*DIN + kk*32 + hi*8]);
    }
    __syncthreads();

#pragma unroll
    for (int ct = 0; ct < 12; ct++) {
        f32x4 acc = {0.f, 0.f, 0.f, 0.f};
#pragma unroll
        for (int kk = 0; kk < 4; kk++) {
            bf16x8 bfrag = *reinterpret_cast<const bf16x8*>(&sW[ct*16 + lo][kk*32 + hi*8]);
            acc = __builtin_amdgcn_mfma_f32_16x16x32_bf16(afrag[kk], bfrag, acc, 0, 0, 0);
        }
#pragma unroll
        for (int r = 0; r < 4; r++) {
            int row = rbase + hi*4 + r;
            if (row < NN) P[(size_t)row*PD + ct*16 + lo] = __float2bfloat16(acc[r]);
        }
    }
}

// ---------------- CSR build (5 small dispatches — empirically fastest) ----------------
__global__ void k_hist(const int* __restrict__ dst, int* __restrict__ counts, int e) {
    int i = blockIdx.x * blockDim.x + threadIdx.x;
    if (i < e) atomicAdd(&counts[dst[i]], 1);
}

__global__ __launch_bounds__(256) void k_bsum(const int* __restrict__ counts,
                                              int* __restrict__ bsum, int n) {
    __shared__ int ws[4];
    const int gid = blockIdx.x * 256 + threadIdx.x;
    const int lane = threadIdx.x & 63, wid = threadIdx.x >> 6;
    int v = (gid < n) ? counts[gid] : 0;
#pragma unroll
    for (int s = 1; s < 64; s <<= 1) v += __shfl_xor(v, s);
    if (lane == 0) ws[wid] = v;
    __syncthreads();
    if (threadIdx.x == 0) bsum[blockIdx.x] = ws[0] + ws[1] + ws[2] + ws[3];
}

__global__ __launch_bounds__(256) void k_bscan(const int* __restrict__ bsum,
                                               int* __restrict__ bpre,
                                               int* __restrict__ offsets, int nb) {
    __shared__ int ws[4];
    const int t = threadIdx.x, lane = t & 63, wid = t >> 6;
    int v = (t < nb) ? bsum[t] : 0;
    int sc = v;
#pragma unroll
    for (int s = 1; s < 64; s <<= 1) { int u = __shfl_up(sc, s); if (lane >= s) sc += u; }
    if (lane == 63) ws[wid] = sc;
    __syncthreads();
    int woff = 0;
    for (int k = 0; k < wid; k++) woff += ws[k];
    if (t < nb) bpre[t] = woff + sc - v;
    if (t == 0) offsets[NN] = NE;
}

__global__ __launch_bounds__(256) void k_apply(const int* __restrict__ counts,
                                               const int* __restrict__ bpre,
                                               int* __restrict__ offsets,
                                               int* __restrict__ cursor, int n) {
    __shared__ int ws[4];
    const int gid = blockIdx.x * 256 + threadIdx.x;
    const int t = threadIdx.x, lane = t & 63, wid = t >> 6;
    int v = (gid < n) ? counts[gid] : 0;
    int sc = v;
#pragma unroll
    for (int s = 1; s < 64; s <<= 1) { int u = __shfl_up(sc, s); if (lane >= s) sc += u; }
    if (lane == 63) ws[wid] = sc;
    __syncthreads();
    int woff = 0;
    for (int k = 0; k < wid; k++) woff += ws[k];
    const int ex = bpre[blockIdx.x] + woff + sc - v;
    if (gid < n) { offsets[gid] = ex; cursor[gid] = ex; }
}

// scatter: CSR slot p -> edge id and permuted src
__global__ void k_scatter(const int* __restrict__ dst, const int* __restrict__ src,
                          int* __restrict__ cursor, int* __restrict__ eidx,
                          int* __restrict__ srcp, int e) {
    int i = blockIdx.x * blockDim.x + threadIdx.x;
    if (i < e) {
        int p = atomicAdd(&cursor[dst[i]], 1);
        eidx[p] = i;
        srcp[p] = src[i];
    }
}

// ---------------- K2: fused edge stage (R9 structure, single barrier) ----------------
// 512 threads / 8 waves / 128 edges. Per-wave async P gathers; MFMA; per-wave
// XOR-swizzled transpose in own tile; P adds as ds_read_b64; logit = 2 shfl.
__global__ __launch_bounds__(512) void k_edge(
    const float* __restrict__ efeats,
    const float* __restrict__ Wf,     // [32][64] f32
    const float* __restrict__ attn,   // [64] f32
    const float* __restrict__ bias,   // [64] f32
    const bf16* __restrict__ P,       // [NN][192] bf16
    const int* __restrict__ src, const int* __restrict__ dst,
    float* __restrict__ f_out,        // [NE][64] f32
    float* __restrict__ el)           // [NE][4] = exp(logit)
{
    // [0,32K): per-wave 4KB tiles (gather sP, then transpose buf); [32K,36K): sWf
    __shared__ __align__(16) char smem[36864];
    __bf16* sWf = reinterpret_cast<__bf16*>(smem + 32768);   // [64 col][32 k]
    const int t = threadIdx.x;
    const int lane = t & 63, wid = t >> 6;
    const int lo = lane & 15, hi = lane >> 4;
    const int e0w = blockIdx.x * 128 + wid * 16;
    const int c4 = (lane & 15) * 4;

    // stage Wf transposed (all threads)
    {
        int k  = t >> 4;
        int cc = (t & 15) * 4;
        f32x4 w4 = *reinterpret_cast<const f32x4*>(&Wf[k * 64 + cc]);
#pragma unroll
        for (int i = 0; i < 4; i++) sWf[(cc + i)*32 + k] = (__bf16)w4[i];
    }
    __syncthreads();

    // per-wave: node indices for this wave's 16 edges (lanes 0..31)
    int sd = 0;
    if (lane < 32) sd = (lane < 16) ? src[e0w + lane] : dst[e0w + lane - 16];

    // per-wave async gathers: 256 x 16B -> spw[2][16][64] bf16 row-major
    __bf16* spw = reinterpret_cast<__bf16*>(smem) + wid * 2048;
#pragma unroll
    for (int q = 0; q < 4; q++) {
        const int c = lane + q * 64;
        const int table = c >> 7, row16 = (c >> 3) & 15, part = c & 7;
        const int nid = __shfl(sd, table * 16 + row16);
        const bf16* g = P + (size_t)nid * PD + table * 64 + part * 8;
        async_copy16(g, reinterpret_cast<__bf16*>(smem) + (size_t)(wid*2048 + q*512));
    }

    bf16x8 afrag = load8_f32_to_bf16(&efeats[(size_t)(e0w + lo)*DEIN + hi*8]);
    bf16x8 bfr[4];
#pragma unroll
    for (int ct = 0; ct < 4; ct++)
        bfr[ct] = *reinterpret_cast<const bf16x8*>(&sWf[(ct*16 + lo)*32 + hi*8]);

    f32x4 att4  = *reinterpret_cast<const f32x4*>(&attn[c4]);
    f32x4 bias4 = *reinterpret_cast<const f32x4*>(&bias[c4]);

    // wait for this wave's own gathers (+ afrag); vmcnt is per-wave
    asm volatile("s_waitcnt vmcnt(0)" ::: "memory");
    __builtin_amdgcn_sched_barrier(0);

    // P pre-reads for the post-transpose positions: one b64 per (table,q)
    bf16x4 pi4[4], pj4[4];
#pragma unroll
    for (int q = 0; q < 4; q++) {
        const int lrow = (lane >> 4) + q*4;
        pi4[q] = *reinterpret_cast<const bf16x4*>(&spw[lrow*64 + c4]);
        pj4[q] = *reinterpret_cast<const bf16x4*>(&spw[1024 + lrow*64 + c4]);
    }

    f32x4 accv[4];
#pragma unroll
    for (int ct = 0; ct < 4; ct++) {
        f32x4 z = {0.f, 0.f, 0.f, 0.f};
        accv[ct] = __builtin_amdgcn_mfma_f32_16x16x32_bf16(afrag, bfr[ct], z, 0, 0, 0);
    }

    // per-wave swizzled transpose into OWN 4KB tile; wave-local DS is in-order,
    // pi4/pj4 reads above already issued -> no block barrier needed.
    float* sOutF = reinterpret_cast<float*>(smem + wid * 4096);   // [16][64] f32
#pragma unroll
    for (int ct = 0; ct < 4; ct++)
#pragma unroll
        for (int r = 0; r < 4; r++)
            sOutF[(hi*4 + r)*64 + ((ct*16 + lo) ^ (hi << 4))] = accv[ct][r];

#pragma unroll
    for (int q = 0; q < 4; q++) {
        const int lrow = (lane >> 4) + q*4;
        f32x4 o = *reinterpret_cast<const f32x4*>(&sOutF[lrow*64 + (c4 ^ (q << 4))]);
        f32x4 x;
#pragma unroll
        for (int i = 0; i < 4; i++) {
            float xv = o[i] + b2f(pi4[q][i]) + b2f(pj4[q][i]) + bias4[i];
            x[i] = xv > 0.f ? xv : NEG_SLOPE * xv;
        }
        *reinterpret_cast<f32x4*>(&f_out[(size_t)(e0w + lrow)*64 + c4]) = x;
        float partial = x[0]*att4[0] + x[1]*att4[1] + x[2]*att4[2] + x[3]*att4[3];
        partial += __shfl_xor(partial, 1);
        partial += __shfl_xor(partial, 2);
        const float ev = __expf(partial);
        if ((lane & 3) == 0)
            el[(size_t)(e0w + lrow)*4 + ((lane & 15) >> 2)] = ev;
    }
}

// ---------------- K4: single-pass aggregation (a=exp stored; no max needed) ----------
__global__ __launch_bounds__(256) void k_aggregate(
    const int* __restrict__ offsets, const int* __restrict__ eidx,
    const int* __restrict__ srcp, const float* __restrict__ el,
    const bf16* __restrict__ P, float* __restrict__ h_out)
{
    const int lane = threadIdx.x & 63;
    const int wid  = threadIdx.x >> 6;
    const int n = blockIdx.x * 4 + wid;
    if (n >= NN) return;
    const int off0 = offsets[n], off1 = offsets[n + 1];
    const int h4 = lane & 3;        // head for load phase
    const int slot4 = lane >> 2;    // 16 slots

    float denp = 0.f, acc = 0.f;
    for (int c0 = off0; c0 < off1; c0 += 16) {
        const int cnt = off1 - c0;
        float a_ld = 0.f;
        int s_ld = 0;
        if (slot4 < cnt) {
            const int e = eidx[c0 + slot4];
            a_ld = el[(size_t)e*4 + h4];
            s_ld = srcp[c0 + slot4];
        }
        denp += a_ld;
#pragma unroll
        for (int q = 0; q < 16; q++) {
            if (q < cnt) {   // wave-uniform tail guard
                const float wq = __shfl(a_ld, (q << 2) | (lane >> 4));
                const int   sq = __shfl(s_ld, q << 2);
                acc += wq * __bfloat162float(P[(size_t)sq*PD + 128 + lane]);
            }
        }
    }
    denp += __shfl_xor(denp, 4);
    denp += __shfl_xor(denp, 8);
    denp += __shfl_xor(denp, 16);
    denp += __shfl_xor(denp, 32);
    const float den = __shfl(denp, lane >> 4);
    h_out[(size_t)n*64 + lane] = (off1 > off0) ? acc / den : 0.f;
}

extern "C" void kernel_launch(void* const* d_in, const int* in_sizes, int n_in,
                              void* d_out, int out_size, void* d_ws, size_t ws_size,
                              hipStream_t stream) {
    const float* nfeats = (const float*)d_in[0];
    const float* efeats = (const float*)d_in[1];
    const float* Wni    = (const float*)d_in[2];
    const float* Wnj    = (const float*)d_in[3];
    const float* Wfij   = (const float*)d_in[4];
    const float* Wnode  = (const float*)d_in[5];
    const float* attn   = (const float*)d_in[6];
    const float* bias   = (const float*)d_in[7];
    const int*   src    = (const int*)d_in[8];
    const int*   dst    = (const int*)d_in[9];

    float* h_out = (float*)d_out;                           // [NN*64]
    float* f_out = (float*)d_out + (size_t)NN * 64;         // [NE*64]

    char* ws = (char*)d_ws;
    size_t off = 0;
    auto carve = [&](size_t bytes) -> void* {
        void* p = ws + off;
        off = (off + bytes + 255) & ~(size_t)255;
        return p;
    };
    const int NB = (NN + 255) / 256;    // 196 scan blocks
    bf16*  P       = (bf16*) carve((size_t)NN * PD * sizeof(bf16));
    float* el      = (float*)carve((size_t)NE * 4 * sizeof(float));
    int*   counts  = (int*)  carve((size_t)NN * sizeof(int));
    int*   cursor  = (int*)  carve((size_t)NN * sizeof(int));
    int*   offsets = (int*)  carve((size_t)(NN + 1) * sizeof(int));
    int*   eidx    = (int*)  carve((size_t)NE * sizeof(int));
    int*   srcp    = (int*)  carve((size_t)NE * sizeof(int));
    int*   bsum    = (int*)  carve((size_t)NB * sizeof(int));
    int*   bpre    = (int*)  carve((size_t)NB * sizeof(int));
    (void)ws_size; (void)in_sizes; (void)n_in; (void)out_size;

    hipLaunchKernelGGL(k_node_gemm, dim3((NN + 127) / 128), dim3(512), 0, stream,
                       nfeats, Wni, Wnj, Wnode, P, counts);
    hipLaunchKernelGGL(k_hist, dim3((NE + 255) / 256), dim3(256), 0, stream,
                       dst, counts, NE);
    hipLaunchKernelGGL(k_bsum, dim3(NB), dim3(256), 0, stream, counts, bsum, NN);
    hipLaunchKernelGGL(k_bscan, dim3(1), dim3(256), 0, stream, bsum, bpre, offsets, NB);
    hipLaunchKernelGGL(k_apply, dim3(NB), dim3(256), 0, stream,
                       counts, bpre, offsets, cursor, NN);
    hipLaunchKernelGGL(k_scatter, dim3((NE + 255) / 256), dim3(256), 0, stream,
                       dst, src, cursor, eidx, srcp, NE);
    hipLaunchKernelGGL(k_edge, dim3(NE / 128), dim3(512), 0, stream,
                       efeats, Wfij, attn, bias, P, src, dst, f_out, el);
    hipLaunchKernelGGL(k_aggregate, dim3((NN + 3) / 4), dim3(256), 0, stream,
                       offsets, eidx, srcp, el, P, h_out);
}

// Round 14
// 228.118 us; speedup vs baseline: 1.8455x; 1.1028x over previous
//
#include <hip/hip_runtime.h>
#include <hip/hip_bf16.h>

#define NN 50000
#define NE 800000
#define DIN 128
#define DEIN 32
#define PD 192          // P row: [0:64) f_ni, [64:128) f_nj, [128:192) h_src(node proj)
#define NEG_SLOPE 0.2f

typedef __bf16 bf16x8 __attribute__((ext_vector_type(8)));
typedef __bf16 bf16x4 __attribute__((ext_vector_type(4)));
typedef float f32x4 __attribute__((ext_vector_type(4)));
using bf16 = __hip_bfloat16;

__device__ inline float b2f(__bf16 b) {
    unsigned short u = __builtin_bit_cast(unsigned short, b);
    return __uint_as_float((unsigned)u << 16);
}

__device__ inline bf16x8 load8_f32_to_bf16(const float* p) {
    f32x4 a = *reinterpret_cast<const f32x4*>(p);
    f32x4 b = *reinterpret_cast<const f32x4*>(p + 4);
    bf16x8 r;
#pragma unroll
    for (int j = 0; j < 4; j++) {
        r[j]     = (__bf16)a[j];
        r[j + 4] = (__bf16)b[j];
    }
    return r;
}

__device__ inline void async_copy16(const void* g, void* lds) {
    __builtin_amdgcn_global_load_lds(
        (const __attribute__((address_space(1))) void*)g,
        (__attribute__((address_space(3))) void*)lds, 16, 0, 0);
}

// ---------------- K1: P = nfeats @ [W_ni | W_nj | W_node] (+ zero counts) --------------
// 512 threads / 8 waves / 128 rows per block; W staged once, transposed LDS.
__global__ __launch_bounds__(512) void k_node_gemm(
    const float* __restrict__ nfeats,
    const float* __restrict__ Wni, const float* __restrict__ Wnj,
    const float* __restrict__ Wnode,
    bf16* __restrict__ P, int* __restrict__ counts)
{
    __shared__ __align__(16) __bf16 sW[192][136];   // 52.2KB, [col][k]
    const int t = threadIdx.x;
    const int lane = t & 63;
    const int wid  = t >> 6;
    const int lo = lane & 15, hi = lane >> 4;

    {   // fused: zero the histogram buffer
        int z = blockIdx.x * 512 + t;
        if (z < NN) counts[z] = 0;
    }

    const float* tabs[3] = {Wni, Wnj, Wnode};
#pragma unroll
    for (int tb = 0; tb < 3; tb++) {
#pragma unroll
        for (int q = 0; q < 4; q++) {
            int flat = t + q * 512;             // 2048 f32x4 per table
            int k  = flat >> 4;
            int c4 = (flat & 15) * 4;
            f32x4 w4 = *reinterpret_cast<const f32x4*>(&tabs[tb][k * 64 + c4]);
#pragma unroll
            for (int i = 0; i < 4; i++)
                sW[tb * 64 + c4 + i][k] = (__bf16)w4[i];
        }
    }

    const int rbase = blockIdx.x * 128 + wid * 16;
    bf16x8 afrag[4];
#pragma unroll
    for (int kk = 0; kk < 4; kk++) {
        int row = rbase + lo; if (row >= NN) row = NN - 1;
        afrag[kk] = load8_f32_to_bf16(&nfeats[(size_t)row*DIN + kk*32 + hi*8]);
    }
    __syncthreads();

#pragma unroll
    for (int ct = 0; ct < 12; ct++) {
        f32x4 acc = {0.f, 0.f, 0.f, 0.f};
#pragma unroll
        for (int kk = 0; kk < 4; kk++) {
            bf16x8 bfrag = *reinterpret_cast<const bf16x8*>(&sW[ct*16 + lo][kk*32 + hi*8]);
            acc = __builtin_amdgcn_mfma_f32_16x16x32_bf16(afrag[kk], bfrag, acc, 0, 0, 0);
        }
#pragma unroll
        for (int r = 0; r < 4; r++) {
            int row = rbase + hi*4 + r;
            if (row < NN) P[(size_t)row*PD + ct*16 + lo] = __float2bfloat16(acc[r]);
        }
    }
}

// ---------------- CSR build (4 dispatches) ----------------
__global__ void k_hist(const int* __restrict__ dst, int* __restrict__ counts, int e) {
    int i = blockIdx.x * blockDim.x + threadIdx.x;
    if (i < e) atomicAdd(&counts[dst[i]], 1);
}

__global__ __launch_bounds__(256) void k_bsum(const int* __restrict__ counts,
                                              int* __restrict__ bsum, int n) {
    __shared__ int ws[4];
    const int gid = blockIdx.x * 256 + threadIdx.x;
    const int lane = threadIdx.x & 63, wid = threadIdx.x >> 6;
    int v = (gid < n) ? counts[gid] : 0;
#pragma unroll
    for (int s = 1; s < 64; s <<= 1) v += __shfl_xor(v, s);
    if (lane == 0) ws[wid] = v;
    __syncthreads();
    if (threadIdx.x == 0) bsum[blockIdx.x] = ws[0] + ws[1] + ws[2] + ws[3];
}

// apply: redundantly scans bsum (nb<=256) for this block's prefix, then
// intra-block scan of counts -> offsets/cursor. (bscan dispatch eliminated)
__global__ __launch_bounds__(256) void k_apply(const int* __restrict__ counts,
                                               const int* __restrict__ bsum,
                                               int* __restrict__ offsets,
                                               int* __restrict__ cursor, int n, int nb) {
    __shared__ int ws[4];
    __shared__ int sbp;
    const int gid = blockIdx.x * 256 + threadIdx.x;
    const int t = threadIdx.x, lane = t & 63, wid = t >> 6;

    // block-level prefix: inclusive wave scan of bsum + cross-wave
    int bv = (t < nb) ? bsum[t] : 0;
    int bs = bv;
#pragma unroll
    for (int s = 1; s < 64; s <<= 1) { int u = __shfl_up(bs, s); if (lane >= s) bs += u; }
    if (lane == 63) ws[wid] = bs;
    __syncthreads();
    int woffb = 0;
    for (int k = 0; k < wid; k++) woffb += ws[k];
    if (t == blockIdx.x) sbp = woffb + bs - bv;     // exclusive prefix of this block
    if (blockIdx.x == 0 && t == 0) offsets[NN] = NE;
    __syncthreads();
    const int bpre_b = sbp;

    int v = (gid < n) ? counts[gid] : 0;
    int sc = v;
#pragma unroll
    for (int s = 1; s < 64; s <<= 1) { int u = __shfl_up(sc, s); if (lane >= s) sc += u; }
    if (lane == 63) ws[wid] = sc;       // safe: prior ws reads completed before barrier
    __syncthreads();
    int woff = 0;
    for (int k = 0; k < wid; k++) woff += ws[k];
    const int ex = bpre_b + woff + sc - v;
    if (gid < n) { offsets[gid] = ex; cursor[gid] = ex; }
}

// scatter: CSR slot p -> edge id and permuted src
__global__ void k_scatter(const int* __restrict__ dst, const int* __restrict__ src,
                          int* __restrict__ cursor, int* __restrict__ eidx,
                          int* __restrict__ srcp, int e) {
    int i = blockIdx.x * blockDim.x + threadIdx.x;
    if (i < e) {
        int p = atomicAdd(&cursor[dst[i]], 1);
        eidx[p] = i;
        srcp[p] = src[i];
    }
}

// ---------------- K2: fused edge stage (227.7µs-proven structure) ----------------
// 512 threads / 8 waves / 128 edges. Per-wave async P gathers; MFMA; per-wave
// XOR-swizzled transpose in own tile; P adds as ds_read_b64; logit = 2 shfl.
__global__ __launch_bounds__(512) void k_edge(
    const float* __restrict__ efeats,
    const float* __restrict__ Wf,     // [32][64] f32
    const float* __restrict__ attn,   // [64] f32
    const float* __restrict__ bias,   // [64] f32
    const bf16* __restrict__ P,       // [NN][192] bf16
    const int* __restrict__ src, const int* __restrict__ dst,
    float* __restrict__ f_out,        // [NE][64] f32
    float* __restrict__ el)           // [NE][4] = exp(logit)
{
    // [0,32K): per-wave 4KB tiles (gather sP, then transpose buf); [32K,36K): sWf
    __shared__ __align__(16) char smem[36864];
    __bf16* sWf = reinterpret_cast<__bf16*>(smem + 32768);   // [64 col][32 k]
    const int t = threadIdx.x;
    const int lane = t & 63, wid = t >> 6;
    const int lo = lane & 15, hi = lane >> 4;
    const int e0w = blockIdx.x * 128 + wid * 16;
    const int c4 = (lane & 15) * 4;

    // stage Wf transposed (all threads)
    {
        int k  = t >> 4;
        int cc = (t & 15) * 4;
        f32x4 w4 = *reinterpret_cast<const f32x4*>(&Wf[k * 64 + cc]);
#pragma unroll
        for (int i = 0; i < 4; i++) sWf[(cc + i)*32 + k] = (__bf16)w4[i];
    }
    __syncthreads();

    // per-wave: node indices for this wave's 16 edges (lanes 0..31)
    int sd = 0;
    if (lane < 32) sd = (lane < 16) ? src[e0w + lane] : dst[e0w + lane - 16];

    // per-wave async gathers: 256 x 16B -> spw[2][16][64] bf16 row-major
    __bf16* spw = reinterpret_cast<__bf16*>(smem) + wid * 2048;
#pragma unroll
    for (int q = 0; q < 4; q++) {
        const int c = lane + q * 64;
        const int table = c >> 7, row16 = (c >> 3) & 15, part = c & 7;
        const int nid = __shfl(sd, table * 16 + row16);
        const bf16* g = P + (size_t)nid * PD + table * 64 + part * 8;
        async_copy16(g, reinterpret_cast<__bf16*>(smem) + (size_t)(wid*2048 + q*512));
    }

    bf16x8 afrag = load8_f32_to_bf16(&efeats[(size_t)(e0w + lo)*DEIN + hi*8]);
    bf16x8 bfr[4];
#pragma unroll
    for (int ct = 0; ct < 4; ct++)
        bfr[ct] = *reinterpret_cast<const bf16x8*>(&sWf[(ct*16 + lo)*32 + hi*8]);

    f32x4 att4  = *reinterpret_cast<const f32x4*>(&attn[c4]);
    f32x4 bias4 = *reinterpret_cast<const f32x4*>(&bias[c4]);

    // wait for this wave's own gathers (+ afrag); vmcnt is per-wave
    asm volatile("s_waitcnt vmcnt(0)" ::: "memory");
    __builtin_amdgcn_sched_barrier(0);

    // P pre-reads for the post-transpose positions: one b64 per (table,q)
    bf16x4 pi4[4], pj4[4];
#pragma unroll
    for (int q = 0; q < 4; q++) {
        const int lrow = (lane >> 4) + q*4;
        pi4[q] = *reinterpret_cast<const bf16x4*>(&spw[lrow*64 + c4]);
        pj4[q] = *reinterpret_cast<const bf16x4*>(&spw[1024 + lrow*64 + c4]);
    }

    f32x4 accv[4];
#pragma unroll
    for (int ct = 0; ct < 4; ct++) {
        f32x4 z = {0.f, 0.f, 0.f, 0.f};
        accv[ct] = __builtin_amdgcn_mfma_f32_16x16x32_bf16(afrag, bfr[ct], z, 0, 0, 0);
    }

    // per-wave swizzled transpose into OWN 4KB tile; wave-local DS is in-order.
    float* sOutF = reinterpret_cast<float*>(smem + wid * 4096);   // [16][64] f32
#pragma unroll
    for (int ct = 0; ct < 4; ct++)
#pragma unroll
        for (int r = 0; r < 4; r++)
            sOutF[(hi*4 + r)*64 + ((ct*16 + lo) ^ (hi << 4))] = accv[ct][r];

#pragma unroll
    for (int q = 0; q < 4; q++) {
        const int lrow = (lane >> 4) + q*4;
        f32x4 o = *reinterpret_cast<const f32x4*>(&sOutF[lrow*64 + (c4 ^ (q << 4))]);
        f32x4 x;
#pragma unroll
        for (int i = 0; i < 4; i++) {
            float xv = o[i] + b2f(pi4[q][i]) + b2f(pj4[q][i]) + bias4[i];
            x[i] = xv > 0.f ? xv : NEG_SLOPE * xv;
        }
        *reinterpret_cast<f32x4*>(&f_out[(size_t)(e0w + lrow)*64 + c4]) = x;
        float partial = x[0]*att4[0] + x[1]*att4[1] + x[2]*att4[2] + x[3]*att4[3];
        partial += __shfl_xor(partial, 1);
        partial += __shfl_xor(partial, 2);
        const float ev = __expf(partial);
        if ((lane & 3) == 0)
            el[(size_t)(e0w + lrow)*4 + ((lane & 15) >> 2)] = ev;
    }
}

// ---------------- K4: single-pass aggregation (unguarded 16-gather, MLP=16) ----------
__global__ __launch_bounds__(256) void k_aggregate(
    const int* __restrict__ offsets, const int* __restrict__ eidx,
    const int* __restrict__ srcp, const float* __restrict__ el,
    const bf16* __restrict__ P, float* __restrict__ h_out)
{
    const int lane = threadIdx.x & 63;
    const int wid  = threadIdx.x >> 6;
    const int n = blockIdx.x * 4 + wid;
    if (n >= NN) return;
    const int off0 = offsets[n], off1 = offsets[n + 1];
    const int h4 = lane & 3;        // head for load phase
    const int slot4 = lane >> 2;    // 16 slots

    float denp = 0.f, acc = 0.f;
    for (int c0 = off0; c0 < off1; c0 += 16) {
        const int cnt = off1 - c0;
        float a_ld = 0.f;
        int s_ld = 0;
        if (slot4 < cnt) {
            const int e = eidx[c0 + slot4];
            a_ld = el[(size_t)e*4 + h4];
            s_ld = srcp[c0 + slot4];
        }
        denp += a_ld;
#pragma unroll
        for (int q = 0; q < 16; q++) {
            const float wq = __shfl(a_ld, (q << 2) | (lane >> 4));
            const int   sq = __shfl(s_ld, q << 2);
            acc += wq * __bfloat162float(P[(size_t)sq*PD + 128 + lane]);
        }
    }
    denp += __shfl_xor(denp, 4);
    denp += __shfl_xor(denp, 8);
    denp += __shfl_xor(denp, 16);
    denp += __shfl_xor(denp, 32);
    const float den = __shfl(denp, lane >> 4);
    h_out[(size_t)n*64 + lane] = (off1 > off0) ? acc / den : 0.f;
}

extern "C" void kernel_launch(void* const* d_in, const int* in_sizes, int n_in,
                              void* d_out, int out_size, void* d_ws, size_t ws_size,
                              hipStream_t stream) {
    const float* nfeats = (const float*)d_in[0];
    const float* efeats = (const float*)d_in[1];
    const float* Wni    = (const float*)d_in[2];
    const float* Wnj    = (const float*)d_in[3];
    const float* Wfij   = (const float*)d_in[4];
    const float* Wnode  = (const float*)d_in[5];
    const float* attn   = (const float*)d_in[6];
    const float* bias   = (const float*)d_in[7];
    const int*   src    = (const int*)d_in[8];
    const int*   dst    = (const int*)d_in[9];

    float* h_out = (float*)d_out;                           // [NN*64]
    float* f_out = (float*)d_out + (size_t)NN * 64;         // [NE*64]

    char* ws = (char*)d_ws;
    size_t off = 0;
    auto carve = [&](size_t bytes) -> void* {
        void* p = ws + off;
        off = (off + bytes + 255) & ~(size_t)255;
        return p;
    };
    const int NB = (NN + 255) / 256;    // 196 scan blocks
    bf16*  P       = (bf16*) carve((size_t)NN * PD * sizeof(bf16));
    float* el      = (float*)carve((size_t)NE * 4 * sizeof(float));
    int*   counts  = (int*)  carve((size_t)NN * sizeof(int));
    int*   cursor  = (int*)  carve((size_t)NN * sizeof(int));
    int*   offsets = (int*)  carve((size_t)(NN + 1) * sizeof(int));
    int*   eidx    = (int*)  carve((size_t)NE * sizeof(int));
    int*   srcp    = (int*)  carve((size_t)NE * sizeof(int));
    int*   bsum    = (int*)  carve((size_t)NB * sizeof(int));
    (void)ws_size; (void)in_sizes; (void)n_in; (void)out_size;

    hipLaunchKernelGGL(k_node_gemm, dim3((NN + 127) / 128), dim3(512), 0, stream,
                       nfeats, Wni, Wnj, Wnode, P, counts);
    hipLaunchKernelGGL(k_hist, dim3((NE + 255) / 256), dim3(256), 0, stream,
                       dst, counts, NE);
    hipLaunchKernelGGL(k_bsum, dim3(NB), dim3(256), 0, stream, counts, bsum, NN);
    hipLaunchKernelGGL(k_apply, dim3(NB), dim3(256), 0, stream,
                       counts, bsum, offsets, cursor, NN, NB);
    hipLaunchKernelGGL(k_scatter, dim3((NE + 255) / 256), dim3(256), 0, stream,
                       dst, src, cursor, eidx, srcp, NE);
    hipLaunchKernelGGL(k_edge, dim3(NE / 128), dim3(512), 0, stream,
                       efeats, Wfij, attn, bias, P, src, dst, f_out, el);
    hipLaunchKernelGGL(k_aggregate, dim3((NN + 3) / 4), dim3(256), 0, stream,
                       offsets, eidx, srcp, el, P, h_out);
}

// Round 15
// 202.947 us; speedup vs baseline: 2.0743x; 1.1240x over previous
//
#include <hip/hip_runtime.h>
#include <hip/hip_bf16.h>

#define NN 50000
#define NE 800000
#define DIN 128
#define DEIN 32
#define PD 192          // P row: [0:64) f_ni, [64:128) f_nj, [128:192) h_src(node proj)
#define NEG_SLOPE 0.2f

typedef __bf16 bf16x8 __attribute__((ext_vector_type(8)));
typedef __bf16 bf16x4 __attribute__((ext_vector_type(4)));
typedef float f32x4 __attribute__((ext_vector_type(4)));
using bf16 = __hip_bfloat16;

__device__ inline float b2f(__bf16 b) {
    unsigned short u = __builtin_bit_cast(unsigned short, b);
    return __uint_as_float((unsigned)u << 16);
}

__device__ inline bf16x8 load8_f32_to_bf16(const float* p) {
    f32x4 a = *reinterpret_cast<const f32x4*>(p);
    f32x4 b = *reinterpret_cast<const f32x4*>(p + 4);
    bf16x8 r;
#pragma unroll
    for (int j = 0; j < 4; j++) {
        r[j]     = (__bf16)a[j];
        r[j + 4] = (__bf16)b[j];
    }
    return r;
}

__device__ inline void async_copy16(const void* g, void* lds) {
    __builtin_amdgcn_global_load_lds(
        (const __attribute__((address_space(1))) void*)g,
        (__attribute__((address_space(3))) void*)lds, 16, 0, 0);
}

// ---------------- K1: P = nfeats @ [W_ni | W_nj | W_node] (+ zero counts) --------------
// 512 threads / 8 waves / 128 rows per block; W staged once, transposed LDS.
__global__ __launch_bounds__(512) void k_node_gemm(
    const float* __restrict__ nfeats,
    const float* __restrict__ Wni, const float* __restrict__ Wnj,
    const float* __restrict__ Wnode,
    bf16* __restrict__ P, int* __restrict__ counts)
{
    __shared__ __align__(16) __bf16 sW[192][136];   // 52.2KB, [col][k]
    const int t = threadIdx.x;
    const int lane = t & 63;
    const int wid  = t >> 6;
    const int lo = lane & 15, hi = lane >> 4;

    {   // fused: zero the histogram buffer
        int z = blockIdx.x * 512 + t;
        if (z < NN) counts[z] = 0;
    }

    const float* tabs[3] = {Wni, Wnj, Wnode};
#pragma unroll
    for (int tb = 0; tb < 3; tb++) {
#pragma unroll
        for (int q = 0; q < 4; q++) {
            int flat = t + q * 512;             // 2048 f32x4 per table
            int k  = flat >> 4;
            int c4 = (flat & 15) * 4;
            f32x4 w4 = *reinterpret_cast<const f32x4*>(&tabs[tb][k * 64 + c4]);
#pragma unroll
            for (int i = 0; i < 4; i++)
                sW[tb * 64 + c4 + i][k] = (__bf16)w4[i];
        }
    }

    const int rbase = blockIdx.x * 128 + wid * 16;
    bf16x8 afrag[4];
#pragma unroll
    for (int kk = 0; kk < 4; kk++) {
        int row = rbase + lo; if (row >= NN) row = NN - 1;
        afrag[kk] = load8_f32_to_bf16(&nfeats[(size_t)row*DIN + kk*32 + hi*8]);
    }
    __syncthreads();

#pragma unroll
    for (int ct = 0; ct < 12; ct++) {
        f32x4 acc = {0.f, 0.f, 0.f, 0.f};
#pragma unroll
        for (int kk = 0; kk < 4; kk++) {
            bf16x8 bfrag = *reinterpret_cast<const bf16x8*>(&sW[ct*16 + lo][kk*32 + hi*8]);
            acc = __builtin_amdgcn_mfma_f32_16x16x32_bf16(afrag[kk], bfrag, acc, 0, 0, 0);
        }
#pragma unroll
        for (int r = 0; r < 4; r++) {
            int row = rbase + hi*4 + r;
            if (row < NN) P[(size_t)row*PD + ct*16 + lo] = __float2bfloat16(acc[r]);
        }
    }
}

// ---------------- K2: fused edge stage + histogram ----------------
// 512 threads / 8 waves / 128 edges. Per-wave async P gathers; MFMA hoisted
// above the vmcnt drain (hides gather latency); per-wave XOR-swizzled
// transpose in own tile; P adds as ds_read_b64; logit = 2 shfl; dst lanes
// do the histogram atomics (replaces the k_hist dispatch).
__global__ __launch_bounds__(512) void k_edge(
    const float* __restrict__ efeats,
    const float* __restrict__ Wf,     // [32][64] f32
    const float* __restrict__ attn,   // [64] f32
    const float* __restrict__ bias,   // [64] f32
    const bf16* __restrict__ P,       // [NN][192] bf16
    const int* __restrict__ src, const int* __restrict__ dst,
    float* __restrict__ f_out,        // [NE][64] f32
    float* __restrict__ el,           // [NE][4] = exp(logit)
    int* __restrict__ counts)         // [NN] histogram (pre-zeroed)
{
    // [0,32K): per-wave 4KB tiles (gather sP, then transpose buf); [32K,36K): sWf
    __shared__ __align__(16) char smem[36864];
    __bf16* sWf = reinterpret_cast<__bf16*>(smem + 32768);   // [64 col][32 k]
    const int t = threadIdx.x;
    const int lane = t & 63, wid = t >> 6;
    const int lo = lane & 15, hi = lane >> 4;
    const int e0w = blockIdx.x * 128 + wid * 16;
    const int c4 = (lane & 15) * 4;

    // stage Wf transposed (all threads)
    {
        int k  = t >> 4;
        int cc = (t & 15) * 4;
        f32x4 w4 = *reinterpret_cast<const f32x4*>(&Wf[k * 64 + cc]);
#pragma unroll
        for (int i = 0; i < 4; i++) sWf[(cc + i)*32 + k] = (__bf16)w4[i];
    }
    __syncthreads();

    // per-wave: node indices for this wave's 16 edges (lanes 0..31)
    int sd = 0;
    if (lane < 32) sd = (lane < 16) ? src[e0w + lane] : dst[e0w + lane - 16];
    // fused histogram: dst lanes count their edge (one atomic per edge total)
    if (lane >= 16 && lane < 32) atomicAdd(&counts[sd], 1);

    // per-wave async gathers: 256 x 16B -> spw[2][16][64] bf16 row-major
    __bf16* spw = reinterpret_cast<__bf16*>(smem) + wid * 2048;
#pragma unroll
    for (int q = 0; q < 4; q++) {
        const int c = lane + q * 64;
        const int table = c >> 7, row16 = (c >> 3) & 15, part = c & 7;
        const int nid = __shfl(sd, table * 16 + row16);
        const bf16* g = P + (size_t)nid * PD + table * 64 + part * 8;
        async_copy16(g, reinterpret_cast<__bf16*>(smem) + (size_t)(wid*2048 + q*512));
    }

    bf16x8 afrag = load8_f32_to_bf16(&efeats[(size_t)(e0w + lo)*DEIN + hi*8]);
    bf16x8 bfr[4];
#pragma unroll
    for (int ct = 0; ct < 4; ct++)
        bfr[ct] = *reinterpret_cast<const bf16x8*>(&sWf[(ct*16 + lo)*32 + hi*8]);

    f32x4 att4  = *reinterpret_cast<const f32x4*>(&attn[c4]);
    f32x4 bias4 = *reinterpret_cast<const f32x4*>(&bias[c4]);

    // MFMA first — depends only on afrag/bfr (compiler-tracked waits);
    // overlaps the in-flight P gathers with compute.
    f32x4 accv[4];
#pragma unroll
    for (int ct = 0; ct < 4; ct++) {
        f32x4 z = {0.f, 0.f, 0.f, 0.f};
        accv[ct] = __builtin_amdgcn_mfma_f32_16x16x32_bf16(afrag, bfr[ct], z, 0, 0, 0);
    }

    // drain this wave's gathers (vmcnt is per-wave) before touching spw
    asm volatile("s_waitcnt vmcnt(0)" ::: "memory");
    __builtin_amdgcn_sched_barrier(0);

    // P pre-reads for the post-transpose positions: one b64 per (table,q)
    bf16x4 pi4[4], pj4[4];
#pragma unroll
    for (int q = 0; q < 4; q++) {
        const int lrow = (lane >> 4) + q*4;
        pi4[q] = *reinterpret_cast<const bf16x4*>(&spw[lrow*64 + c4]);
        pj4[q] = *reinterpret_cast<const bf16x4*>(&spw[1024 + lrow*64 + c4]);
    }

    // per-wave swizzled transpose into OWN 4KB tile; wave-local DS is in-order
    // (pi4/pj4 reads issued above precede these writes in the DS pipe).
    float* sOutF = reinterpret_cast<float*>(smem + wid * 4096);   // [16][64] f32
#pragma unroll
    for (int ct = 0; ct < 4; ct++)
#pragma unroll
        for (int r = 0; r < 4; r++)
            sOutF[(hi*4 + r)*64 + ((ct*16 + lo) ^ (hi << 4))] = accv[ct][r];

#pragma unroll
    for (int q = 0; q < 4; q++) {
        const int lrow = (lane >> 4) + q*4;
        f32x4 o = *reinterpret_cast<const f32x4*>(&sOutF[lrow*64 + (c4 ^ (q << 4))]);
        f32x4 x;
#pragma unroll
        for (int i = 0; i < 4; i++) {
            float xv = o[i] + b2f(pi4[q][i]) + b2f(pj4[q][i]) + bias4[i];
            x[i] = xv > 0.f ? xv : NEG_SLOPE * xv;
        }
        *reinterpret_cast<f32x4*>(&f_out[(size_t)(e0w + lrow)*64 + c4]) = x;
        float partial = x[0]*att4[0] + x[1]*att4[1] + x[2]*att4[2] + x[3]*att4[3];
        partial += __shfl_xor(partial, 1);
        partial += __shfl_xor(partial, 2);
        const float ev = __expf(partial);
        if ((lane & 3) == 0)
            el[(size_t)(e0w + lrow)*4 + ((lane & 15) >> 2)] = ev;
    }
}

// ---------------- CSR build (3 dispatches after edge) ----------------
__global__ __launch_bounds__(256) void k_bsum(const int* __restrict__ counts,
                                              int* __restrict__ bsum, int n) {
    __shared__ int ws[4];
    const int gid = blockIdx.x * 256 + threadIdx.x;
    const int lane = threadIdx.x & 63, wid = threadIdx.x >> 6;
    int v = (gid < n) ? counts[gid] : 0;
#pragma unroll
    for (int s = 1; s < 64; s <<= 1) v += __shfl_xor(v, s);
    if (lane == 0) ws[wid] = v;
    __syncthreads();
    if (threadIdx.x == 0) bsum[blockIdx.x] = ws[0] + ws[1] + ws[2] + ws[3];
}

// apply: redundantly scans bsum (nb<=256) for this block's prefix, then
// intra-block scan of counts -> offsets/cursor.
__global__ __launch_bounds__(256) void k_apply(const int* __restrict__ counts,
                                               const int* __restrict__ bsum,
                                               int* __restrict__ offsets,
                                               int* __restrict__ cursor, int n, int nb) {
    __shared__ int ws[4];
    __shared__ int sbp;
    const int gid = blockIdx.x * 256 + threadIdx.x;
    const int t = threadIdx.x, lane = t & 63, wid = t >> 6;

    int bv = (t < nb) ? bsum[t] : 0;
    int bs = bv;
#pragma unroll
    for (int s = 1; s < 64; s <<= 1) { int u = __shfl_up(bs, s); if (lane >= s) bs += u; }
    if (lane == 63) ws[wid] = bs;
    __syncthreads();
    int woffb = 0;
    for (int k = 0; k < wid; k++) woffb += ws[k];
    if (t == blockIdx.x) sbp = woffb + bs - bv;     // exclusive prefix of this block
    if (blockIdx.x == 0 && t == 0) offsets[NN] = NE;
    __syncthreads();
    const int bpre_b = sbp;

    int v = (gid < n) ? counts[gid] : 0;
    int sc = v;
#pragma unroll
    for (int s = 1; s < 64; s <<= 1) { int u = __shfl_up(sc, s); if (lane >= s) sc += u; }
    if (lane == 63) ws[wid] = sc;
    __syncthreads();
    int woff = 0;
    for (int k = 0; k < wid; k++) woff += ws[k];
    const int ex = bpre_b + woff + sc - v;
    if (gid < n) { offsets[gid] = ex; cursor[gid] = ex; }
}

// scatter: CSR slot p -> edge id and permuted src
__global__ void k_scatter(const int* __restrict__ dst, const int* __restrict__ src,
                          int* __restrict__ cursor, int* __restrict__ eidx,
                          int* __restrict__ srcp, int e) {
    int i = blockIdx.x * blockDim.x + threadIdx.x;
    if (i < e) {
        int p = atomicAdd(&cursor[dst[i]], 1);
        eidx[p] = i;
        srcp[p] = src[i];
    }
}

// ---------------- K4: single-pass aggregation (unguarded 16-gather, MLP=16) ----------
__global__ __launch_bounds__(256) void k_aggregate(
    const int* __restrict__ offsets, const int* __restrict__ eidx,
    const int* __restrict__ srcp, const float* __restrict__ el,
    const bf16* __restrict__ P, float* __restrict__ h_out)
{
    const int lane = threadIdx.x & 63;
    const int wid  = threadIdx.x >> 6;
    const int n = blockIdx.x * 4 + wid;
    if (n >= NN) return;
    const int off0 = offsets[n], off1 = offsets[n + 1];
    const int h4 = lane & 3;        // head for load phase
    const int slot4 = lane >> 2;    // 16 slots

    float denp = 0.f, acc = 0.f;
    for (int c0 = off0; c0 < off1; c0 += 16) {
        const int cnt = off1 - c0;
        float a_ld = 0.f;
        int s_ld = 0;
        if (slot4 < cnt) {
            const int e = eidx[c0 + slot4];
            a_ld = el[(size_t)e*4 + h4];
            s_ld = srcp[c0 + slot4];
        }
        denp += a_ld;
#pragma unroll
        for (int q = 0; q < 16; q++) {
            const float wq = __shfl(a_ld, (q << 2) | (lane >> 4));
            const int   sq = __shfl(s_ld, q << 2);
            acc += wq * __bfloat162float(P[(size_t)sq*PD + 128 + lane]);
        }
    }
    denp += __shfl_xor(denp, 4);
    denp += __shfl_xor(denp, 8);
    denp += __shfl_xor(denp, 16);
    denp += __shfl_xor(denp, 32);
    const float den = __shfl(denp, lane >> 4);
    h_out[(size_t)n*64 + lane] = (off1 > off0) ? acc / den : 0.f;
}

extern "C" void kernel_launch(void* const* d_in, const int* in_sizes, int n_in,
                              void* d_out, int out_size, void* d_ws, size_t ws_size,
                              hipStream_t stream) {
    const float* nfeats = (const float*)d_in[0];
    const float* efeats = (const float*)d_in[1];
    const float* Wni    = (const float*)d_in[2];
    const float* Wnj    = (const float*)d_in[3];
    const float* Wfij   = (const float*)d_in[4];
    const float* Wnode  = (const float*)d_in[5];
    const float* attn   = (const float*)d_in[6];
    const float* bias   = (const float*)d_in[7];
    const int*   src    = (const int*)d_in[8];
    const int*   dst    = (const int*)d_in[9];

    float* h_out = (float*)d_out;                           // [NN*64]
    float* f_out = (float*)d_out + (size_t)NN * 64;         // [NE*64]

    char* ws = (char*)d_ws;
    size_t off = 0;
    auto carve = [&](size_t bytes) -> void* {
        void* p = ws + off;
        off = (off + bytes + 255) & ~(size_t)255;
        return p;
    };
    const int NB = (NN + 255) / 256;    // 196 scan blocks
    bf16*  P       = (bf16*) carve((size_t)NN * PD * sizeof(bf16));
    float* el      = (float*)carve((size_t)NE * 4 * sizeof(float));
    int*   counts  = (int*)  carve((size_t)NN * sizeof(int));
    int*   cursor  = (int*)  carve((size_t)NN * sizeof(int));
    int*   offsets = (int*)  carve((size_t)(NN + 1) * sizeof(int));
    int*   eidx    = (int*)  carve((size_t)NE * sizeof(int));
    int*   srcp    = (int*)  carve((size_t)NE * sizeof(int));
    int*   bsum    = (int*)  carve((size_t)NB * sizeof(int));
    (void)ws_size; (void)in_sizes; (void)n_in; (void)out_size;

    hipLaunchKernelGGL(k_node_gemm, dim3((NN + 127) / 128), dim3(512), 0, stream,
                       nfeats, Wni, Wnj, Wnode, P, counts);
    hipLaunchKernelGGL(k_edge, dim3(NE / 128), dim3(512), 0, stream,
                       efeats, Wfij, attn, bias, P, src, dst, f_out, el, counts);
    hipLaunchKernelGGL(k_bsum, dim3(NB), dim3(256), 0, stream, counts, bsum, NN);
    hipLaunchKernelGGL(k_apply, dim3(NB), dim3(256), 0, stream,
                       counts, bsum, offsets, cursor, NN, NB);
    hipLaunchKernelGGL(k_scatter, dim3((NE + 255) / 256), dim3(256), 0, stream,
                       dst, src, cursor, eidx, srcp, NE);
    hipLaunchKernelGGL(k_aggregate, dim3((NN + 3) / 4), dim3(256), 0, stream,
                       offsets, eidx, srcp, el, P, h_out);
}